// Round 8
// baseline (13745.004 us; speedup 1.0000x reference)
//
#include <hip/hip_runtime.h>
#include <cstdint>
#include <cstddef>

#define BATCH   8
#define NPTS    16384
#define CFEAT   64
#define NPOINT  2048
#define NSAMPLE 32
#define DIN     124
#define D1      128
#define D2      128
#define D3      256
#define LN_EPS  1e-5f

#define GD      8
#define NCELL   512   // 8x8x8

// sorted point storage (module BSS; avoids ws_size assumptions)
__device__ float          g_sx[BATCH][NPTS];
__device__ float          g_sy[BATCH][NPTS];
__device__ float          g_sz[BATCH][NPTS];
__device__ unsigned short g_so[BATCH][NPTS];   // original index
__device__ unsigned short g_sc[BATCH][NPTS];   // cell id

#define PTS16(F) F(0) F(1) F(2) F(3) F(4) F(5) F(6) F(7) \
                 F(8) F(9) F(10) F(11) F(12) F(13) F(14) F(15)

// ---------------------------------------------------------------------------
// Kernel 1: grid-pruned farthest point sampling. One block per batch.
// Points counting-sorted by 8^3 grid cell (setup, once). Per step, a cell is
// recomputed only if dlb2(centroid, cell) < cellmax * (1+1e-4); otherwise all
// its values (and its contribution to the argmax) are bit-identical cached.
// Skips are provably exact: d_comp(p,c) >= dlb_comp*(1-6e-7) for p in cell.
// Exact reference math elsewhere: __fsub/__fmul/__fadd (no contraction),
// fminf, argmax tie-break on ORIGINAL index via packed u64 (val, ~oidx).
// ---------------------------------------------------------------------------
__attribute__((amdgpu_waves_per_eu(4, 4)))
__global__ __launch_bounds__(1024) void fps_kernel(
    const float* __restrict__ xyz, int* __restrict__ fps_idx,
    float* __restrict__ new_xyz)
{
  const int b = blockIdx.x;
  const int t = threadIdx.x;
  const float* X = xyz + (size_t)b * NPTS * 3;

  __shared__ float          s_mind[16 * 1024];     // 64 KB [k*1024+t]
  __shared__ unsigned short s_oidx[16 * 1024];     // 32 KB [k*1024+t]
  __shared__ float          cellmaxv[NCELL];       // f32 max mindist (-1 = empty)
  __shared__ unsigned char  cflag[NCELL];
  __shared__ unsigned int   cstart[NCELL + 1];
  __shared__ unsigned int   ccur[NCELL];
  __shared__ unsigned short tscid[1024][8];        // 16 KB
  __shared__ unsigned char  tsend[1024][8];        // 8 KB
  __shared__ unsigned long long wvp[16];
  __shared__ float          cbuf[3];
  __shared__ float          redbuf[16][6];
  __shared__ float          gpar[9];               // lox..z, isx..z, cwx..z

  unsigned int* cmu = (unsigned int*)cellmaxv;

#define DECLP(i) float px##i, py##i, pz##i;
  PTS16(DECLP)
#undef DECLP

  // ---- load original strided layout ----
#define LOADP(i) { int j = t + (i << 10);  \
    px##i = X[3 * j + 0];                  \
    py##i = X[3 * j + 1];                  \
    pz##i = X[3 * j + 2]; }
  PTS16(LOADP)
#undef LOADP

  // ---- bbox reduce ----
  {
    float mnx = px0, mxx = px0, mny = py0, mxy = py0, mnz = pz0, mxz = pz0;
#define BB(i) { mnx = fminf(mnx, px##i); mxx = fmaxf(mxx, px##i);  \
                mny = fminf(mny, py##i); mxy = fmaxf(mxy, py##i);  \
                mnz = fminf(mnz, pz##i); mxz = fmaxf(mxz, pz##i); }
    PTS16(BB)
#undef BB
#pragma unroll
    for (int off = 32; off >= 1; off >>= 1) {
      mnx = fminf(mnx, __shfl_xor(mnx, off)); mxx = fmaxf(mxx, __shfl_xor(mxx, off));
      mny = fminf(mny, __shfl_xor(mny, off)); mxy = fmaxf(mxy, __shfl_xor(mxy, off));
      mnz = fminf(mnz, __shfl_xor(mnz, off)); mxz = fmaxf(mxz, __shfl_xor(mxz, off));
    }
    if ((t & 63) == 0) {
      int w = t >> 6;
      redbuf[w][0] = mnx; redbuf[w][1] = mxx; redbuf[w][2] = mny;
      redbuf[w][3] = mxy; redbuf[w][4] = mnz; redbuf[w][5] = mxz;
    }
    __syncthreads();
    if (t == 0) {
      float a0 = redbuf[0][0], a1 = redbuf[0][1], a2 = redbuf[0][2];
      float a3 = redbuf[0][3], a4 = redbuf[0][4], a5 = redbuf[0][5];
      for (int w = 1; w < 16; ++w) {
        a0 = fminf(a0, redbuf[w][0]); a1 = fmaxf(a1, redbuf[w][1]);
        a2 = fminf(a2, redbuf[w][2]); a3 = fmaxf(a3, redbuf[w][3]);
        a4 = fminf(a4, redbuf[w][4]); a5 = fmaxf(a5, redbuf[w][5]);
      }
      float rx = a1 - a0, ry = a3 - a2, rz = a5 - a4;
      gpar[0] = a0; gpar[1] = a2; gpar[2] = a4;
      gpar[3] = (rx > 1e-20f) ? (float)GD / rx : 0.f;
      gpar[4] = (ry > 1e-20f) ? (float)GD / ry : 0.f;
      gpar[5] = (rz > 1e-20f) ? (float)GD / rz : 0.f;
      gpar[6] = rx * (1.0f / GD); gpar[7] = ry * (1.0f / GD); gpar[8] = rz * (1.0f / GD);
      cbuf[0] = X[0]; cbuf[1] = X[1]; cbuf[2] = X[2];
    }
    if (t < NCELL + 1) cstart[t] = 0;
    __syncthreads();
  }

#define CELLOF(x, y, z) ({                                             \
    int ix_ = (int)((x - gpar[0]) * gpar[3]);                          \
    int iy_ = (int)((y - gpar[1]) * gpar[4]);                          \
    int iz_ = (int)((z - gpar[2]) * gpar[5]);                          \
    ix_ = ix_ < 0 ? 0 : (ix_ > GD - 1 ? GD - 1 : ix_);                 \
    iy_ = iy_ < 0 ? 0 : (iy_ > GD - 1 ? GD - 1 : iy_);                 \
    iz_ = iz_ < 0 ? 0 : (iz_ > GD - 1 ? GD - 1 : iz_);                 \
    ix_ + (iy_ << 3) + (iz_ << 6); })

  // ---- histogram ----
#define CIDK(i) int cid##i = CELLOF(px##i, py##i, pz##i); \
    atomicAdd(&cstart[cid##i + 1], 1u);
  PTS16(CIDK)
#undef CIDK
  __syncthreads();

  // ---- prefix scan (wave 0) ----
  if (t < 64) {
    unsigned v[8], p[8];
    unsigned run = 0;
#pragma unroll
    for (int j = 0; j < 8; ++j) { v[j] = cstart[t * 8 + 1 + j]; run += v[j]; p[j] = run; }
    unsigned tot = run;
#pragma unroll
    for (int off = 1; off < 64; off <<= 1) {
      unsigned u = __shfl_up(run, off);
      if ((t & 63) >= off) run += u;
    }
    unsigned excl = run - tot;
    if (t == 0) cstart[0] = 0;
#pragma unroll
    for (int j = 0; j < 8; ++j) cstart[t * 8 + 1 + j] = excl + p[j];
  }
  __syncthreads();
  if (t < NCELL) ccur[t] = cstart[t];
  __syncthreads();

  // ---- scatter to global (sorted SoA) ----
#define SCATK(i) { unsigned dst = atomicAdd(&ccur[cid##i], 1u);        \
    g_sx[b][dst] = px##i; g_sy[b][dst] = py##i; g_sz[b][dst] = pz##i;  \
    g_so[b][dst] = (unsigned short)(t + (i << 10));                    \
    g_sc[b][dst] = (unsigned short)cid##i; }
  PTS16(SCATK)
#undef SCATK
  __syncthreads();   // vmcnt drained before barrier by compiler

  // ---- reload sorted (consecutive per thread), init state ----
  int mno = 0x7fffffff, kmn = 0;
#define RELK(i) { int p_ = (t << 4) + i;                               \
    px##i = g_sx[b][p_]; py##i = g_sy[b][p_]; pz##i = g_sz[b][p_];     \
    unsigned short oo_ = g_so[b][p_];                                  \
    s_oidx[(i << 10) + t] = oo_;                                       \
    s_mind[(i << 10) + t] = 1e10f;                                     \
    if ((int)oo_ < mno) { mno = oo_; kmn = i; } }
  PTS16(RELK)
#undef RELK

  // ---- per-thread segment table (cells are contiguous after sort) ----
  {
    int ns = 0, prevc = -1; bool ovf = false;
#define SEGB(i) { int c_ = CELLOF(px##i, py##i, pz##i);                \
    if (c_ != prevc) {                                                 \
      if (ns < 8) { tscid[t][ns] = (unsigned short)c_;                 \
        if (ns > 0) tsend[t][ns - 1] = (unsigned char)i; ns++; }       \
      else ovf = true;                                                 \
      prevc = c_; } }
    PTS16(SEGB)
#undef SEGB
    if (!ovf) {
      tsend[t][ns - 1] = 16;
      for (int j = ns; j < 8; ++j) { tscid[t][j] = tscid[t][ns - 1]; tsend[t][j] = 16; }
    } else {
      tsend[t][0] = 0xFF;
    }
  }
  if (t < NCELL) {
    unsigned cnt = cstart[t + 1] - cstart[t];
    cellmaxv[t] = cnt ? 1e10f : -1.0f;
    cflag[t] = 0;
  }

  // per-thread argmax cache: all values 1e10 -> smallest orig idx wins
  unsigned long long tc =
      ((unsigned long long)__float_as_uint(1e10f) << 32) |
      (unsigned)(~(unsigned)mno);
  int kc = kmn;
  int far = 0;
  __syncthreads();

  // ======================= main FPS loop =======================
  for (int s = 0; s < NPOINT; ++s) {
    const float cx = cbuf[0], cy = cbuf[1], cz = cbuf[2];
    if (t == 0) {
      fps_idx[b * NPOINT + s] = far;
      float* o = new_xyz + ((size_t)b * NPOINT + s) * 3;
      o[0] = cx; o[1] = cy; o[2] = cz;
    }
    if (s == NPOINT - 1) break;

    // ---- P1: cell bound tests ----
    if (t < NCELL) {
      float mv = cellmaxv[t];
      int ix = t & 7, iy = (t >> 3) & 7, iz = t >> 6;
      float lx = gpar[0] + ix * gpar[6], hx = lx + gpar[6];
      float ly = gpar[1] + iy * gpar[7], hy = ly + gpar[7];
      float lz = gpar[2] + iz * gpar[8], hz = lz + gpar[8];
      float dx = fmaxf(fmaxf(lx - cx, cx - hx), 0.f);
      float dy = fmaxf(fmaxf(ly - cy, cy - hy), 0.f);
      float dz = fmaxf(fmaxf(lz - cz, cz - hz), 0.f);
      float dlb2 = dx * dx + dy * dy + dz * dz;
      bool dirty = dlb2 < mv * 1.0001f;
      cflag[t] = dirty ? 1 : 0;
      if (dirty) cmu[t] = 0u;   // = 0.0f; refreshed by atomicMax below
    }
    __syncthreads();   // B1

    // ---- P2: update dirty cells, maintain caches ----
    unsigned mask = 0;
    {
      unsigned long long ev = *(const unsigned long long*)&tsend[t][0];
      if ((ev & 0xFF) != 0xFF) {
        uint4 sv = *(const uint4*)&tscid[t][0];
        unsigned short sc[8];
        sc[0] = sv.x & 0xFFFF; sc[1] = sv.x >> 16;
        sc[2] = sv.y & 0xFFFF; sc[3] = sv.y >> 16;
        sc[4] = sv.z & 0xFFFF; sc[5] = sv.z >> 16;
        sc[6] = sv.w & 0xFFFF; sc[7] = sv.w >> 16;
        int ks = 0;
#pragma unroll
        for (int sg = 0; sg < 8; ++sg) {
          int ce = (int)((ev >> (sg * 8)) & 0xFF);
          if (ce > ks) {
            if (cflag[sc[sg]])
              mask |= ((ce == 16 ? 0xFFFFu : ((1u << ce) - 1u)) & ~((1u << ks) - 1u));
            ks = ce;
          }
        }
        if (mask) {
#define DSTEP(i) if (mask & (1u << i)) {                                   \
    float dx = __fsub_rn(px##i, cx);                                       \
    float dy = __fsub_rn(py##i, cy);                                       \
    float dz = __fsub_rn(pz##i, cz);                                       \
    float d  = __fadd_rn(__fadd_rn(__fmul_rn(dx, dx), __fmul_rn(dy, dy)),  \
                         __fmul_rn(dz, dz));                               \
    float nd = fminf(s_mind[(i << 10) + t], d);                            \
    s_mind[(i << 10) + t] = nd; }
          PTS16(DSTEP)
#undef DSTEP
          // per-segment cell-max refresh (one atomic per touched segment)
          int ks2 = 0;
#pragma unroll
          for (int sg = 0; sg < 8; ++sg) {
            int ce = (int)((ev >> (sg * 8)) & 0xFF);
            if (ce > ks2) {
              if (mask & (1u << ks2)) {
                float m = 0.f;
                for (int k2 = ks2; k2 < ce; ++k2)
                  m = fmaxf(m, s_mind[(k2 << 10) + t]);
                atomicMax(&cmu[sc[sg]], __float_as_uint(m));
              }
              ks2 = ce;
            }
          }
        }
      } else {
        // fallback: >8 distinct cells (sparse periphery)
        const unsigned short* gp = &g_sc[b][t << 4];
        for (int k2 = 0; k2 < 16; ++k2) {
          unsigned short c2 = gp[k2];
          if (cflag[c2]) mask |= (1u << k2);
        }
        if (mask) {
#define FDSTEP(i) if (mask & (1u << i)) {                                  \
    float dx = __fsub_rn(px##i, cx);                                       \
    float dy = __fsub_rn(py##i, cy);                                       \
    float dz = __fsub_rn(pz##i, cz);                                       \
    float d  = __fadd_rn(__fadd_rn(__fmul_rn(dx, dx), __fmul_rn(dy, dy)),  \
                         __fmul_rn(dz, dz));                               \
    float nd = fminf(s_mind[(i << 10) + t], d);                            \
    s_mind[(i << 10) + t] = nd;                                            \
    atomicMax(&cmu[gp[i]], __float_as_uint(nd)); }
          PTS16(FDSTEP)
#undef FDSTEP
        }
      }
      // cache: rescan only if cached-max point's cell was dirty
      if (mask & (1u << kc)) {
        unsigned long long best = 0; int bk = 0;
        for (int k2 = 0; k2 < 16; ++k2) {
          float v = s_mind[(k2 << 10) + t];
          unsigned long long pk =
              ((unsigned long long)__float_as_uint(v) << 32) |
              (unsigned)(~(unsigned)s_oidx[(k2 << 10) + t]);
          if (pk > best) { best = pk; bk = k2; }
        }
        tc = best; kc = bk;
      }
    }
    // wave cache refresh only if wave saw dirty points
    if (__any(mask != 0)) {
      unsigned long long r = tc;
#pragma unroll
      for (int off = 32; off >= 1; off >>= 1) {
        unsigned long long o = __shfl_xor(r, off);
        if (o > r) r = o;
      }
      if ((t & 63) == 0) wvp[t >> 6] = r;
    }
    __syncthreads();   // B2

    // ---- stage 2 (redundant) + winner broadcast ----
    unsigned long long g = wvp[0];
#pragma unroll
    for (int w = 1; w < 16; ++w) { unsigned long long v = wvp[w]; if (v > g) g = v; }
    far = (int)(unsigned short)(~(unsigned)g);
    if (tc == g) {
#define OWNK(i) if (kc == i) { cbuf[0] = px##i; cbuf[1] = py##i; cbuf[2] = pz##i; }
      PTS16(OWNK)
#undef OWNK
    }
    __syncthreads();   // B3
  }
#undef CELLOF
}

// ---------------------------------------------------------------------------
// Kernel 2: exact 32-NN per centroid (unchanged from r7, passing).
// ---------------------------------------------------------------------------
__attribute__((amdgpu_waves_per_eu(2, 2)))
__global__ __launch_bounds__(256) void knn_kernel(
    const float* __restrict__ xyz, const float* __restrict__ new_xyz,
    int* __restrict__ knn_idx)
{
  const int lane = threadIdx.x & 63;
  const int wid  = threadIdx.x >> 6;
  const int gidbase = blockIdx.x * 64 + wid * 16;
  const int b = gidbase / NPOINT;
  const float* X = xyz + (size_t)b * NPTS * 3;

  float cx[16], cy[16], cz[16];
#pragma unroll
  for (int c = 0; c < 16; ++c) {
    const float* p = new_xyz + (size_t)(gidbase + c) * 3;
    cx[c] = p[0]; cy[c] = p[1]; cz[c] = p[2];
  }

  float qd[16]; int qi[16]; float T[16];
#pragma unroll
  for (int c = 0; c < 16; ++c) { qd[c] = 3.4e38f; qi[c] = 0; T[c] = 3.4e38f; }

  for (int base = 0; base < NPTS; base += 64) {
    const int j = base + lane;
    const float x = X[3 * j + 0];
    const float y = X[3 * j + 1];
    const float z = X[3 * j + 2];
#pragma unroll
    for (int c = 0; c < 16; ++c) {
      float dx = __fsub_rn(x, cx[c]);
      float dy = __fsub_rn(y, cy[c]);
      float dz = __fsub_rn(z, cz[c]);
      float v  = __fadd_rn(__fadd_rn(__fmul_rn(dx, dx), __fmul_rn(dy, dy)),
                           __fmul_rn(dz, dz));
      unsigned long long m = __ballot(v < T[c]);
      while (m) {
        int bit = __ffsll(m) - 1;
        m &= m - 1;
        float vb = __shfl(v, bit);
        if (vb < T[c]) {
          int   jb = base + bit;
          float du = __shfl_up(qd[c], 1);
          int   iu = __shfl_up(qi[c], 1);
          bool c2 = (lane > 0) && (vb < du);
          bool c1 = vb < qd[c];
          qd[c] = c2 ? du : (c1 ? vb : qd[c]);
          qi[c] = c2 ? iu : (c1 ? jb : qi[c]);
          T[c] = __shfl(qd[c], 31);
        }
      }
    }
  }
#pragma unroll
  for (int c = 0; c < 16; ++c) {
    if (lane < 32) knn_idx[(size_t)(gidbase + c) * NSAMPLE + lane] = qi[c];
  }
}

// ---------------------------------------------------------------------------
// Kernel 3: gather + NeRF encoding + 3-layer MLP (f32) + max over k
// (unchanged from r7, passing).
// ---------------------------------------------------------------------------
__attribute__((amdgpu_waves_per_eu(4, 4)))
__global__ __launch_bounds__(128) void mlp_kernel(
    const float* __restrict__ xyz, const float* __restrict__ features,
    const float* __restrict__ new_xyz, const int* __restrict__ knn_idx,
    const float* __restrict__ W1, const float* __restrict__ b1,
    const float* __restrict__ g1, const float* __restrict__ be1,
    const float* __restrict__ W2, const float* __restrict__ b2,
    const float* __restrict__ g2, const float* __restrict__ be2,
    const float* __restrict__ W3, const float* __restrict__ b3,
    float* __restrict__ out)
{
  const int g = blockIdx.x;
  const int b = g / NPOINT;
  const int t = threadIdx.x;

  __shared__ float bufT[128 * 36];
  __shared__ int   ki[32];
  __shared__ float cen[3];
  __shared__ float red[32][4][2];
  __shared__ float lnp[32][2];

  if (t < 32) ki[t] = knn_idx[(size_t)g * NSAMPLE + t];
  if (t < 3)  cen[t] = new_xyz[(size_t)g * 3 + t];
  __syncthreads();

  {
    int r = t & 31, cs = (t >> 5) << 4;
    const float* frow = features + ((size_t)b * NPTS + ki[r]) * CFEAT + cs;
#pragma unroll
    for (int u = 0; u < 4; ++u) {
      float4 f = *(const float4*)(frow + 4 * u);
      bufT[(cs + 4 * u + 0) * 36 + r] = f.x;
      bufT[(cs + 4 * u + 1) * 36 + r] = f.y;
      bufT[(cs + 4 * u + 2) * 36 + r] = f.z;
      bufT[(cs + 4 * u + 3) * 36 + r] = f.w;
    }
  }
  if (t < 32) {
    const float* p = xyz + ((size_t)b * NPTS + ki[t]) * 3;
    float rx = p[0] - cen[0];
    float ry = p[1] - cen[1];
    float rz = p[2] - cen[2];
#pragma unroll
    for (int l = 0; l < 10; ++l) {
      float sc = (float)(1 << l);
      float ax = rx * sc, ay = ry * sc, az = rz * sc;
      int base = (64 + l * 6) * 36 + t;
      bufT[base + 0 * 36] = __sinf(ax);
      bufT[base + 1 * 36] = __sinf(ay);
      bufT[base + 2 * 36] = __sinf(az);
      bufT[base + 3 * 36] = __cosf(ax);
      bufT[base + 4 * 36] = __cosf(ay);
      bufT[base + 5 * 36] = __cosf(az);
    }
  }
  __syncthreads();

  float acc[32];

  {
    float bias = b1[t];
#pragma unroll
    for (int r = 0; r < 32; ++r) acc[r] = bias;
    for (int i = 0; i < DIN; ++i) {
      float w = W1[i * D1 + t];
      const float* hr = &bufT[i * 36];
#pragma unroll
      for (int r = 0; r < 32; ++r) acc[r] = fmaf(hr[r], w, acc[r]);
    }
  }
  {
    __syncthreads();
#pragma unroll
    for (int r = 0; r < 32; ++r) bufT[t * 36 + r] = acc[r];
    __syncthreads();
    {
      int r = t & 31, seg = t >> 5;
      float s = 0.f, ss = 0.f;
#pragma unroll
      for (int u = 0; u < 32; ++u) {
        float v = bufT[(seg * 32 + u) * 36 + r];
        s += v; ss = fmaf(v, v, ss);
      }
      red[r][seg][0] = s; red[r][seg][1] = ss;
    }
    __syncthreads();
    if (t < 32) {
      float s  = red[t][0][0] + red[t][1][0] + red[t][2][0] + red[t][3][0];
      float ss = red[t][0][1] + red[t][1][1] + red[t][2][1] + red[t][3][1];
      float m  = s * (1.0f / D1);
      float var = ss * (1.0f / D1) - m * m;
      lnp[t][0] = m;
      lnp[t][1] = rsqrtf(var + LN_EPS);
    }
    __syncthreads();
    float gg = g1[t], bb = be1[t];
#pragma unroll
    for (int r = 0; r < 32; ++r) {
      float v = (acc[r] - lnp[r][0]) * lnp[r][1];
      v = fmaf(v, gg, bb);
      bufT[t * 36 + r] = fmaxf(v, 0.f);
    }
    __syncthreads();
  }

  {
    float bias = b2[t];
#pragma unroll
    for (int r = 0; r < 32; ++r) acc[r] = bias;
    for (int i = 0; i < D1; ++i) {
      float w = W2[i * D2 + t];
      const float* hr = &bufT[i * 36];
#pragma unroll
      for (int r = 0; r < 32; ++r) acc[r] = fmaf(hr[r], w, acc[r]);
    }
  }
  {
    __syncthreads();
#pragma unroll
    for (int r = 0; r < 32; ++r) bufT[t * 36 + r] = acc[r];
    __syncthreads();
    {
      int r = t & 31, seg = t >> 5;
      float s = 0.f, ss = 0.f;
#pragma unroll
      for (int u = 0; u < 32; ++u) {
        float v = bufT[(seg * 32 + u) * 36 + r];
        s += v; ss = fmaf(v, v, ss);
      }
      red[r][seg][0] = s; red[r][seg][1] = ss;
    }
    __syncthreads();
    if (t < 32) {
      float s  = red[t][0][0] + red[t][1][0] + red[t][2][0] + red[t][3][0];
      float ss = red[t][0][1] + red[t][1][1] + red[t][2][1] + red[t][3][1];
      float m  = s * (1.0f / D2);
      float var = ss * (1.0f / D2) - m * m;
      lnp[t][0] = m;
      lnp[t][1] = rsqrtf(var + LN_EPS);
    }
    __syncthreads();
    float gg = g2[t], bb = be2[t];
#pragma unroll
    for (int r = 0; r < 32; ++r) {
      float v = (acc[r] - lnp[r][0]) * lnp[r][1];
      v = fmaf(v, gg, bb);
      bufT[t * 36 + r] = fmaxf(v, 0.f);
    }
    __syncthreads();
  }

  {
    float a0[32], a1[32];
    float bias0 = b3[t], bias1 = b3[t + 128];
#pragma unroll
    for (int r = 0; r < 32; ++r) { a0[r] = bias0; a1[r] = bias1; }
    for (int i = 0; i < D2; ++i) {
      float w0 = W3[i * D3 + t];
      float w1 = W3[i * D3 + t + 128];
      const float* hr = &bufT[i * 36];
#pragma unroll
      for (int r = 0; r < 32; ++r) {
        a0[r] = fmaf(hr[r], w0, a0[r]);
        a1[r] = fmaf(hr[r], w1, a1[r]);
      }
    }
    float m0 = a0[0], m1 = a1[0];
#pragma unroll
    for (int r = 1; r < 32; ++r) { m0 = fmaxf(m0, a0[r]); m1 = fmaxf(m1, a1[r]); }
    float* of = out + (size_t)g * D3;
    of[t] = m0;
    of[t + 128] = m1;
  }
}

// ---------------------------------------------------------------------------
extern "C" void kernel_launch(void* const* d_in, const int* in_sizes, int n_in,
                              void* d_out, int out_size, void* d_ws, size_t ws_size,
                              hipStream_t stream) {
  const float* xyz      = (const float*)d_in[0];
  const float* features = (const float*)d_in[1];
  const float* W1  = (const float*)d_in[2];
  const float* b1  = (const float*)d_in[3];
  const float* g1  = (const float*)d_in[4];
  const float* be1 = (const float*)d_in[5];
  const float* W2  = (const float*)d_in[6];
  const float* b2  = (const float*)d_in[7];
  const float* g2  = (const float*)d_in[8];
  const float* be2 = (const float*)d_in[9];
  const float* W3  = (const float*)d_in[10];
  const float* b3  = (const float*)d_in[11];

  float* new_xyz  = (float*)d_out;
  float* new_feat = (float*)d_out + (size_t)BATCH * NPOINT * 3;

  int* fps_idx = (int*)d_ws;
  int* knn_idx = fps_idx + BATCH * NPOINT;

  fps_kernel<<<dim3(BATCH), dim3(1024), 0, stream>>>(xyz, fps_idx, new_xyz);
  knn_kernel<<<dim3((BATCH * NPOINT) / 64), dim3(256), 0, stream>>>(xyz, new_xyz, knn_idx);
  mlp_kernel<<<dim3(BATCH * NPOINT), dim3(128), 0, stream>>>(
      xyz, features, new_xyz, knn_idx,
      W1, b1, g1, be1, W2, b2, g2, be2, W3, b3, new_feat);
}

// Round 9
// 5995.108 us; speedup vs baseline: 2.2927x; 2.2927x over previous
//
#include <hip/hip_runtime.h>
#include <cstdint>
#include <cstddef>

#define BATCH   8
#define NPTS    16384
#define CFEAT   64
#define NPOINT  2048
#define NSAMPLE 32
#define DIN     124
#define D1      128
#define D2      128
#define D3      256
#define LN_EPS  1e-5f

#define PTS16(F) F(0) F(1) F(2) F(3) F(4) F(5) F(6) F(7) \
                 F(8) F(9) F(10) F(11) F(12) F(13) F(14) F(15)

// ---------------------------------------------------------------------------
// Kernel 1: brute-force FPS, value-only argmax (r9).
// One block per batch, 1024 threads, 16 pts/thread. Coords in 48 named
// registers (asm-pinned, r7-proven no-spill at 56 VGPRs); min-dist in LDS.
// Hot path per point: 8 exact-rounded distance ops + LDS read/min/write +
// ONE v_max_f32 (no per-point index tracking). Wave reduce and stage-2 are
// f32-only (shfl_xor max; 4x ds_read_b128 broadcast + max tree). Index
// recovered off the hot path: threads whose local max == block max (bit
// equality; >=1 thread) rescan their 16 dists for the smallest matching k
// and atomicMax a packed (g_bits<<32 | ~origidx) u64 -> smallest original
// index wins ties, matching jnp.argmax exactly. Owner thread writes its
// register coords to cbuf (bit-identical).
// Exact reference f32 math: separate __fsub/__fmul/__fadd (no FMA
// contraction), fminf.
// ---------------------------------------------------------------------------
__attribute__((amdgpu_waves_per_eu(4, 4)))
__global__ __launch_bounds__(1024) void fps_kernel(
    const float* __restrict__ xyz, int* __restrict__ fps_idx,
    float* __restrict__ new_xyz)
{
  const int b = blockIdx.x;
  const int t = threadIdx.x;
  const float* X = xyz + (size_t)b * NPTS * 3;

  __shared__ float s_mind[16 * 1024];            // 64 KB, [k*1024 + t]
  __shared__ float wvv[16];                      // per-wave f32 max
  __shared__ unsigned long long s_packed;        // (g_bits<<32)|~origidx
  __shared__ float cbuf[3];

#define DECLP(i) float px##i, py##i, pz##i;
  PTS16(DECLP)
#undef DECLP

#define LOADP(i) { int j = t + (i << 10);  \
    px##i = X[3 * j + 0];                  \
    py##i = X[3 * j + 1];                  \
    pz##i = X[3 * j + 2];                  \
    s_mind[(i << 10) + t] = 1e10f; }
  PTS16(LOADP)
#undef LOADP

  if (t == 0) { cbuf[0] = X[0]; cbuf[1] = X[1]; cbuf[2] = X[2]; }
  int far = 0;
  __syncthreads();

  for (int s = 0; s < NPOINT; ++s) {
    const float cx = cbuf[0], cy = cbuf[1], cz = cbuf[2];
    if (t == 0) {
      fps_idx[b * NPOINT + s] = far;
      float* o = new_xyz + ((size_t)b * NPOINT + s) * 3;
      o[0] = cx; o[1] = cy; o[2] = cz;
      s_packed = 0ull;                  // reset for this step's atomicMax
    }
    if (s == NPOINT - 1) break;

    // pin coords in VGPRs (blocks spill/remat; r7-proven)
    asm volatile("" : "+v"(px0), "+v"(px1), "+v"(px2), "+v"(px3),
                      "+v"(px4), "+v"(px5), "+v"(px6), "+v"(px7),
                      "+v"(px8), "+v"(px9), "+v"(px10), "+v"(px11),
                      "+v"(px12), "+v"(px13), "+v"(px14), "+v"(px15));
    asm volatile("" : "+v"(py0), "+v"(py1), "+v"(py2), "+v"(py3),
                      "+v"(py4), "+v"(py5), "+v"(py6), "+v"(py7),
                      "+v"(py8), "+v"(py9), "+v"(py10), "+v"(py11),
                      "+v"(py12), "+v"(py13), "+v"(py14), "+v"(py15));
    asm volatile("" : "+v"(pz0), "+v"(pz1), "+v"(pz2), "+v"(pz3),
                      "+v"(pz4), "+v"(pz5), "+v"(pz6), "+v"(pz7),
                      "+v"(pz8), "+v"(pz9), "+v"(pz10), "+v"(pz11),
                      "+v"(pz12), "+v"(pz13), "+v"(pz14), "+v"(pz15));

    float mybest = -1.0f;
#define STEP(i) {                                                        \
    float dx = __fsub_rn(px##i, cx);                                     \
    float dy = __fsub_rn(py##i, cy);                                     \
    float dz = __fsub_rn(pz##i, cz);                                     \
    float d  = __fadd_rn(__fadd_rn(__fmul_rn(dx, dx), __fmul_rn(dy, dy)),\
                         __fmul_rn(dz, dz));                             \
    float nd = fminf(s_mind[(i << 10) + t], d);                          \
    s_mind[(i << 10) + t] = nd;                                          \
    mybest = fmaxf(mybest, nd); }
    PTS16(STEP)
#undef STEP

    // f32-only wave max
    float wmax = mybest;
#pragma unroll
    for (int off = 32; off >= 1; off >>= 1)
      wmax = fmaxf(wmax, __shfl_xor(wmax, off));
    if ((t & 63) == 0) wvv[t >> 6] = wmax;
    __syncthreads();   // B1

    // stage 2 (redundant, f32): 4x b128 broadcast + max tree
    float4 v0 = *(const float4*)&wvv[0];
    float4 v1 = *(const float4*)&wvv[4];
    float4 v2 = *(const float4*)&wvv[8];
    float4 v3 = *(const float4*)&wvv[12];
    float g = fmaxf(
        fmaxf(fmaxf(fmaxf(v0.x, v0.y), fmaxf(v0.z, v0.w)),
              fmaxf(fmaxf(v1.x, v1.y), fmaxf(v1.z, v1.w))),
        fmaxf(fmaxf(fmaxf(v2.x, v2.y), fmaxf(v2.z, v2.w)),
              fmaxf(fmaxf(v3.x, v3.y), fmaxf(v3.z, v3.w))));

    // winners (bit-exact match; usually 1 thread) recover smallest index
    if (mybest == g) {
      int kk = 0;
#pragma unroll
      for (int k = 15; k >= 0; --k)
        if (s_mind[(k << 10) + t] == g) kk = k;
      unsigned idx = (unsigned)(t + (kk << 10));
      unsigned long long pk =
          ((unsigned long long)__float_as_uint(g) << 32) | (unsigned)(~idx);
      atomicMax(&s_packed, pk);
    }
    __syncthreads();   // B2

    unsigned long long gp = s_packed;
    int widx = (int)(~(unsigned)(gp & 0xffffffffull)) & 0x3fff;
    far = widx;
    if (t == (widx & 1023)) {
      int c = widx >> 10;
#define OWNK(i) if (c == i) { cbuf[0] = px##i; cbuf[1] = py##i; cbuf[2] = pz##i; }
      PTS16(OWNK)
#undef OWNK
    }
    __syncthreads();   // B3
  }
}

// ---------------------------------------------------------------------------
// Kernel 2: exact 32-NN per centroid (r7 version, passing).
// ---------------------------------------------------------------------------
__attribute__((amdgpu_waves_per_eu(2, 2)))
__global__ __launch_bounds__(256) void knn_kernel(
    const float* __restrict__ xyz, const float* __restrict__ new_xyz,
    int* __restrict__ knn_idx)
{
  const int lane = threadIdx.x & 63;
  const int wid  = threadIdx.x >> 6;
  const int gidbase = blockIdx.x * 64 + wid * 16;
  const int b = gidbase / NPOINT;
  const float* X = xyz + (size_t)b * NPTS * 3;

  float cx[16], cy[16], cz[16];
#pragma unroll
  for (int c = 0; c < 16; ++c) {
    const float* p = new_xyz + (size_t)(gidbase + c) * 3;
    cx[c] = p[0]; cy[c] = p[1]; cz[c] = p[2];
  }

  float qd[16]; int qi[16]; float T[16];
#pragma unroll
  for (int c = 0; c < 16; ++c) { qd[c] = 3.4e38f; qi[c] = 0; T[c] = 3.4e38f; }

  for (int base = 0; base < NPTS; base += 64) {
    const int j = base + lane;
    const float x = X[3 * j + 0];
    const float y = X[3 * j + 1];
    const float z = X[3 * j + 2];
#pragma unroll
    for (int c = 0; c < 16; ++c) {
      float dx = __fsub_rn(x, cx[c]);
      float dy = __fsub_rn(y, cy[c]);
      float dz = __fsub_rn(z, cz[c]);
      float v  = __fadd_rn(__fadd_rn(__fmul_rn(dx, dx), __fmul_rn(dy, dy)),
                           __fmul_rn(dz, dz));
      unsigned long long m = __ballot(v < T[c]);
      while (m) {
        int bit = __ffsll(m) - 1;
        m &= m - 1;
        float vb = __shfl(v, bit);
        if (vb < T[c]) {
          int   jb = base + bit;
          float du = __shfl_up(qd[c], 1);
          int   iu = __shfl_up(qi[c], 1);
          bool c2 = (lane > 0) && (vb < du);
          bool c1 = vb < qd[c];
          qd[c] = c2 ? du : (c1 ? vb : qd[c]);
          qi[c] = c2 ? iu : (c1 ? jb : qi[c]);
          T[c] = __shfl(qd[c], 31);
        }
      }
    }
  }
#pragma unroll
  for (int c = 0; c < 16; ++c) {
    if (lane < 32) knn_idx[(size_t)(gidbase + c) * NSAMPLE + lane] = qi[c];
  }
}

// ---------------------------------------------------------------------------
// Kernel 3: gather + NeRF encoding + 3-layer MLP (f32) + max over k
// (r7 version, passing).
// ---------------------------------------------------------------------------
__attribute__((amdgpu_waves_per_eu(4, 4)))
__global__ __launch_bounds__(128) void mlp_kernel(
    const float* __restrict__ xyz, const float* __restrict__ features,
    const float* __restrict__ new_xyz, const int* __restrict__ knn_idx,
    const float* __restrict__ W1, const float* __restrict__ b1,
    const float* __restrict__ g1, const float* __restrict__ be1,
    const float* __restrict__ W2, const float* __restrict__ b2,
    const float* __restrict__ g2, const float* __restrict__ be2,
    const float* __restrict__ W3, const float* __restrict__ b3,
    float* __restrict__ out)
{
  const int g = blockIdx.x;
  const int b = g / NPOINT;
  const int t = threadIdx.x;

  __shared__ float bufT[128 * 36];
  __shared__ int   ki[32];
  __shared__ float cen[3];
  __shared__ float red[32][4][2];
  __shared__ float lnp[32][2];

  if (t < 32) ki[t] = knn_idx[(size_t)g * NSAMPLE + t];
  if (t < 3)  cen[t] = new_xyz[(size_t)g * 3 + t];
  __syncthreads();

  {
    int r = t & 31, cs = (t >> 5) << 4;
    const float* frow = features + ((size_t)b * NPTS + ki[r]) * CFEAT + cs;
#pragma unroll
    for (int u = 0; u < 4; ++u) {
      float4 f = *(const float4*)(frow + 4 * u);
      bufT[(cs + 4 * u + 0) * 36 + r] = f.x;
      bufT[(cs + 4 * u + 1) * 36 + r] = f.y;
      bufT[(cs + 4 * u + 2) * 36 + r] = f.z;
      bufT[(cs + 4 * u + 3) * 36 + r] = f.w;
    }
  }
  if (t < 32) {
    const float* p = xyz + ((size_t)b * NPTS + ki[t]) * 3;
    float rx = p[0] - cen[0];
    float ry = p[1] - cen[1];
    float rz = p[2] - cen[2];
#pragma unroll
    for (int l = 0; l < 10; ++l) {
      float sc = (float)(1 << l);
      float ax = rx * sc, ay = ry * sc, az = rz * sc;
      int base = (64 + l * 6) * 36 + t;
      bufT[base + 0 * 36] = __sinf(ax);
      bufT[base + 1 * 36] = __sinf(ay);
      bufT[base + 2 * 36] = __sinf(az);
      bufT[base + 3 * 36] = __cosf(ax);
      bufT[base + 4 * 36] = __cosf(ay);
      bufT[base + 5 * 36] = __cosf(az);
    }
  }
  __syncthreads();

  float acc[32];

  {
    float bias = b1[t];
#pragma unroll
    for (int r = 0; r < 32; ++r) acc[r] = bias;
    for (int i = 0; i < DIN; ++i) {
      float w = W1[i * D1 + t];
      const float* hr = &bufT[i * 36];
#pragma unroll
      for (int r = 0; r < 32; ++r) acc[r] = fmaf(hr[r], w, acc[r]);
    }
  }
  {
    __syncthreads();
#pragma unroll
    for (int r = 0; r < 32; ++r) bufT[t * 36 + r] = acc[r];
    __syncthreads();
    {
      int r = t & 31, seg = t >> 5;
      float s = 0.f, ss = 0.f;
#pragma unroll
      for (int u = 0; u < 32; ++u) {
        float v = bufT[(seg * 32 + u) * 36 + r];
        s += v; ss = fmaf(v, v, ss);
      }
      red[r][seg][0] = s; red[r][seg][1] = ss;
    }
    __syncthreads();
    if (t < 32) {
      float s  = red[t][0][0] + red[t][1][0] + red[t][2][0] + red[t][3][0];
      float ss = red[t][0][1] + red[t][1][1] + red[t][2][1] + red[t][3][1];
      float m  = s * (1.0f / D1);
      float var = ss * (1.0f / D1) - m * m;
      lnp[t][0] = m;
      lnp[t][1] = rsqrtf(var + LN_EPS);
    }
    __syncthreads();
    float gg = g1[t], bb = be1[t];
#pragma unroll
    for (int r = 0; r < 32; ++r) {
      float v = (acc[r] - lnp[r][0]) * lnp[r][1];
      v = fmaf(v, gg, bb);
      bufT[t * 36 + r] = fmaxf(v, 0.f);
    }
    __syncthreads();
  }

  {
    float bias = b2[t];
#pragma unroll
    for (int r = 0; r < 32; ++r) acc[r] = bias;
    for (int i = 0; i < D1; ++i) {
      float w = W2[i * D2 + t];
      const float* hr = &bufT[i * 36];
#pragma unroll
      for (int r = 0; r < 32; ++r) acc[r] = fmaf(hr[r], w, acc[r]);
    }
  }
  {
    __syncthreads();
#pragma unroll
    for (int r = 0; r < 32; ++r) bufT[t * 36 + r] = acc[r];
    __syncthreads();
    {
      int r = t & 31, seg = t >> 5;
      float s = 0.f, ss = 0.f;
#pragma unroll
      for (int u = 0; u < 32; ++u) {
        float v = bufT[(seg * 32 + u) * 36 + r];
        s += v; ss = fmaf(v, v, ss);
      }
      red[r][seg][0] = s; red[r][seg][1] = ss;
    }
    __syncthreads();
    if (t < 32) {
      float s  = red[t][0][0] + red[t][1][0] + red[t][2][0] + red[t][3][0];
      float ss = red[t][0][1] + red[t][1][1] + red[t][2][1] + red[t][3][1];
      float m  = s * (1.0f / D2);
      float var = ss * (1.0f / D2) - m * m;
      lnp[t][0] = m;
      lnp[t][1] = rsqrtf(var + LN_EPS);
    }
    __syncthreads();
    float gg = g2[t], bb = be2[t];
#pragma unroll
    for (int r = 0; r < 32; ++r) {
      float v = (acc[r] - lnp[r][0]) * lnp[r][1];
      v = fmaf(v, gg, bb);
      bufT[t * 36 + r] = fmaxf(v, 0.f);
    }
    __syncthreads();
  }

  {
    float a0[32], a1[32];
    float bias0 = b3[t], bias1 = b3[t + 128];
#pragma unroll
    for (int r = 0; r < 32; ++r) { a0[r] = bias0; a1[r] = bias1; }
    for (int i = 0; i < D2; ++i) {
      float w0 = W3[i * D3 + t];
      float w1 = W3[i * D3 + t + 128];
      const float* hr = &bufT[i * 36];
#pragma unroll
      for (int r = 0; r < 32; ++r) {
        a0[r] = fmaf(hr[r], w0, a0[r]);
        a1[r] = fmaf(hr[r], w1, a1[r]);
      }
    }
    float m0 = a0[0], m1 = a1[0];
#pragma unroll
    for (int r = 1; r < 32; ++r) { m0 = fmaxf(m0, a0[r]); m1 = fmaxf(m1, a1[r]); }
    float* of = out + (size_t)g * D3;
    of[t] = m0;
    of[t + 128] = m1;
  }
}

// ---------------------------------------------------------------------------
extern "C" void kernel_launch(void* const* d_in, const int* in_sizes, int n_in,
                              void* d_out, int out_size, void* d_ws, size_t ws_size,
                              hipStream_t stream) {
  const float* xyz      = (const float*)d_in[0];
  const float* features = (const float*)d_in[1];
  const float* W1  = (const float*)d_in[2];
  const float* b1  = (const float*)d_in[3];
  const float* g1  = (const float*)d_in[4];
  const float* be1 = (const float*)d_in[5];
  const float* W2  = (const float*)d_in[6];
  const float* b2  = (const float*)d_in[7];
  const float* g2  = (const float*)d_in[8];
  const float* be2 = (const float*)d_in[9];
  const float* W3  = (const float*)d_in[10];
  const float* b3  = (const float*)d_in[11];

  float* new_xyz  = (float*)d_out;
  float* new_feat = (float*)d_out + (size_t)BATCH * NPOINT * 3;

  int* fps_idx = (int*)d_ws;
  int* knn_idx = fps_idx + BATCH * NPOINT;

  fps_kernel<<<dim3(BATCH), dim3(1024), 0, stream>>>(xyz, fps_idx, new_xyz);
  knn_kernel<<<dim3((BATCH * NPOINT) / 64), dim3(256), 0, stream>>>(xyz, new_xyz, knn_idx);
  mlp_kernel<<<dim3(BATCH * NPOINT), dim3(128), 0, stream>>>(
      xyz, features, new_xyz, knn_idx,
      W1, b1, g1, be1, W2, b2, g2, be2, W3, b3, new_feat);
}